// Round 9
// baseline (19105.280 us; speedup 1.0000x reference)
//
#include <hip/hip_runtime.h>
#include <stdint.h>
#include <stddef.h>

#define T_SEQ  512
#define NBATCH 64
#define EMBED  512
#define HIDDEN 1024
#define VOCAB  32000
#define NWG    256                    // one WG per CU; each WG = L0 half + L1 half
#define NTHR   512
#define AGENT  __HIP_MEMORY_SCOPE_AGENT
#define WGSCOPE __HIP_MEMORY_SCOPE_WORKGROUP
#define RING   260                    // h ring slots: [64][ h1(1024) | h0(1024) ] bf16
#define SLOT_E (NBATCH * 2048)
#define BOUND  250                    // max L0 lead over L1 (ring-WAR bound)

#define RST   66                      // reduce-buffer row stride (floats)
#define PB    (16 * RST)              // one wave's partial: 16 rows x 64 batch

// flag line for (layer l, step t): 8 chunk counters (128 h-dims each) in one
// 128B line. chunk c's producers: the 32 WGs with (w>>5)==c; target 32.
#define FLG(cnt, l, t)  ((cnt) + ((((t) << 1) | (l)) << 5))
#define AGG1(cnt, t)    ((cnt) + ((1024 + (t)) << 5))   // L1 per-step aggregate, target 256
#define INITC(cnt)      ((cnt) + (1540 << 5))           // init rendezvous, target 256

typedef __attribute__((ext_vector_type(8))) short short8;
typedef __attribute__((ext_vector_type(4))) float f32x4;

__device__ __forceinline__ unsigned short f2bf(float x) {
  union { float f; unsigned u; } v; v.f = x;
  unsigned r = v.u + 0x7FFFu + ((v.u >> 16) & 1u);   // round-to-nearest-even
  return (unsigned short)(r >> 16);
}
__device__ __forceinline__ float sigm(float x) { return 1.0f / (1.0f + __expf(-x)); }
__device__ __forceinline__ float tanh_(float x) {
  float e = __expf(2.0f * x);
  return 1.0f - 2.0f / (e + 1.0f);
}

__device__ __forceinline__ unsigned ld_flag(unsigned* p) {
  return __hip_atomic_load(p, __ATOMIC_RELAXED, AGENT);
}
__device__ __forceinline__ void wait_flag(unsigned* p, unsigned tgt) {
  while (__hip_atomic_load(p, __ATOMIC_RELAXED, AGENT) < tgt)
    __builtin_amdgcn_s_sleep(2);
  asm volatile("" ::: "memory");
}
__device__ __forceinline__ void lds_add(unsigned* p) {
  __hip_atomic_fetch_add(p, 1u, __ATOMIC_RELAXED, WGSCOPE);
}
__device__ __forceinline__ void lds_wait(unsigned* p, unsigned tgt) {
  while (__hip_atomic_load(p, __ATOMIC_RELAXED, WGSCOPE) < tgt)
    __builtin_amdgcn_s_sleep(1);
  asm volatile("" ::: "memory");
}

// ---------------- embedding gather + bf16 cast: xs[t][b][e] ----------------
__global__ void embed_k(const int* __restrict__ texts, const float* __restrict__ emb,
                        unsigned short* __restrict__ xs) {
  const int bid = blockIdx.x;          // t*64 + b
  const int t = bid >> 6, b = bid & 63;
  const int row = texts[b * T_SEQ + t];
  const float* src = emb + (size_t)row * EMBED;
  const int e = threadIdx.x * 2;
  float2 v = *(const float2*)(src + e);
  unsigned pk = (unsigned)f2bf(v.x) | ((unsigned)f2bf(v.y) << 16);
  *(unsigned*)(xs + (size_t)bid * EMBED + e) = pk;
}

// ---------------- one layer-half: 4 waves, 4 hidden dims, K-split 4 ----------------
// Ring slot s: [64][2048]: cols 0-1023 = h1(s-1), cols 1024-2047 = h0(s-1).
// L0 step t: reads slot[t] cols 1024+ (h0(t-1)) + xs[t]; writes slot[t+1] hi.
// L1 step t: waves 0-1 read slot[t] cols 0-1023 (h1(t-1)); waves 2-3 read
//            slot[t+1] cols 1024+ (h0(t)); writes slot[t+1] lo.
// Intra-half sync via LDS counters, one arrive per wave (lane 0):
// lc[0]=partials written, lc[1]=h-stores drained, lc[2]=partials consumed.
template<int LAYER>
__device__ __forceinline__ void run_half(
    const unsigned short* __restrict__ xs_all,
    unsigned short* __restrict__ state,
    unsigned* __restrict__ cnt,
    const float* __restrict__ W0, const float* __restrict__ W1,
    const float* __restrict__ W2, const float* __restrict__ W3,
    const float* __restrict__ B0, const float* __restrict__ B1,
    const float* __restrict__ B2, const float* __restrict__ B3,
    float* bufh, unsigned* lc, int w, int th)
{
  constexpr int K  = LAYER ? 2048 : 1536;
  constexpr int KT = K / 128;              // 16 / 12 K-tiles per wave
  const int lane = th & 63;
  const int wv   = th >> 6;                // wave id within half = K-quarter
  const int ln   = lane & 15;
  const int qq   = lane >> 4;
  const int d    = th & 3;                 // this thread's dim within 4
  const int b    = th >> 2;                // batch... th>>2 in [0,64) only for th<256 ✓
  const int gk   = w * 4 + d;
  const bool l0  = (lane == 0);

  // ---- stage weights into VGPRs: one 16-row m-tile (4 rows per gate) ----
  short8 wreg[KT];
  {
    const float* Wg = (ln < 4) ? W0 : (ln < 8) ? W1 : (ln < 12) ? W2 : W3;
    const float* row = Wg + (size_t)(w * 4 + (ln & 3)) * K;
    #pragma unroll
    for (int kt = 0; kt < KT; ++kt) {
      int col;
      if (LAYER == 1) col = wv * 512 + kt * 32;
      else col = (kt < 4) ? (1024 + wv * 128 + kt * 32) : (wv * 256 + (kt - 4) * 32);
      col += qq * 8;
      f32x4 lo = *(const f32x4*)(row + col);
      f32x4 hi = *(const f32x4*)(row + col + 4);
      short8 v;
      v[0] = (short)f2bf(lo[0]); v[1] = (short)f2bf(lo[1]);
      v[2] = (short)f2bf(lo[2]); v[3] = (short)f2bf(lo[3]);
      v[4] = (short)f2bf(hi[0]); v[5] = (short)f2bf(hi[1]);
      v[6] = (short)f2bf(hi[2]); v[7] = (short)f2bf(hi[3]);
      wreg[kt] = v;
    }
  }
  const float bsf = B0[gk], bsi = B1[gk], bso = B2[gk], bsc = B3[gk];
  float cst = 0.0f;

  wait_flag(INITC(cnt), NWG);              // slot 0 zeroed everywhere

  for (int t = 0; t < T_SEQ; ++t) {
    const int so  = t % RING;
    const int so1 = (t + 1) % RING;
    const unsigned short* slotT  = state + (size_t)so  * SLOT_E;
    const unsigned short* slotT1 = state + (size_t)so1 * SLOT_E;

    lds_wait(lc + 2, 4u * t);              // prev step's partials fully consumed

    unsigned war = 256;                    // ring-WAR prefetch (L0 only)
    if (LAYER == 0 && t >= BOUND) war = ld_flag(AGG1(cnt, t - BOUND));

    f32x4 acc[4] = {};
    if constexpr (LAYER == 0) {
      unsigned* flp = FLG(cnt, 0, (t > 0) ? t - 1 : 0) + 2 * wv;
      unsigned fv0 = 32u, fv1 = 32u;
      if (t > 0) { fv0 = ld_flag(flp); fv1 = ld_flag(flp + 1); }  // prefetch

      // x-phase (static input): overlaps flag/handoff latency
      const unsigned short* xrow = xs_all + (size_t)t * (NBATCH * EMBED);
      #pragma unroll
      for (int kt = 0; kt < 4; ++kt) {
        const int bc = wv * 128 + kt * 32 + qq * 8;
        short8 bf[4];
        #pragma unroll
        for (int nt = 0; nt < 4; ++nt)
          bf[nt] = *(const short8*)(xrow + (size_t)(nt * 16 + ln) * EMBED + bc);
        #pragma unroll
        for (int nt = 0; nt < 4; ++nt)
          acc[nt] = __builtin_amdgcn_mfma_f32_16x16x32_bf16(
              wreg[kt], bf[nt], acc[nt], 0, 0, 0);
      }
      // h-phase: 2 chunks of 128 dims, each gated by its own max-of-32 flag
      const unsigned short* hbase = slotT + 1024;
      #pragma unroll
      for (int c = 0; c < 2; ++c) {
        if (t > 0 && (c ? fv1 : fv0) < 32u) wait_flag(flp + c, 32u);
        asm volatile("" ::: "memory");
        #pragma unroll
        for (int k2 = 0; k2 < 4; ++k2) {
          const int kt = 4 + c * 4 + k2;
          const int hc = wv * 256 + c * 128 + k2 * 32 + qq * 8;
          short8 bf[4];
          #pragma unroll
          for (int nt = 0; nt < 4; ++nt)
            bf[nt] = *(const short8*)(hbase + (size_t)(nt * 16 + ln) * 2048 + hc);
          #pragma unroll
          for (int nt = 0; nt < 4; ++nt)
            acc[nt] = __builtin_amdgcn_mfma_f32_16x16x32_bf16(
                wreg[kt], bf[nt], acc[nt], 0, 0, 0);
        }
      }
    } else {
      // waves 0-1: h1(t-1) = slot[t].lo; waves 2-3: h0(t) = slot[t+1].hi
      unsigned* flp = (wv < 2) ? FLG(cnt, 1, (t > 0) ? t - 1 : 0) + 4 * wv
                               : FLG(cnt, 0, t) + 4 * (wv - 2);
      const bool need = (wv >= 2) || (t > 0);
      unsigned fv[4] = {32u, 32u, 32u, 32u};
      if (need) {
        fv[0] = ld_flag(flp);     fv[1] = ld_flag(flp + 1);
        fv[2] = ld_flag(flp + 2); fv[3] = ld_flag(flp + 3);
      }
      const unsigned short* base = (wv < 2) ? slotT : (slotT1 + 1024);
      const int coff = (wv < 2) ? wv * 512 : (wv - 2) * 512;
      #pragma unroll
      for (int c = 0; c < 4; ++c) {
        if (need && fv[c] < 32u) wait_flag(flp + c, 32u);
        asm volatile("" ::: "memory");
        #pragma unroll
        for (int k2 = 0; k2 < 4; ++k2) {
          const int kt = c * 4 + k2;
          const int cc = coff + c * 128 + k2 * 32 + qq * 8;
          short8 bf[4];
          #pragma unroll
          for (int nt = 0; nt < 4; ++nt)
            bf[nt] = *(const short8*)(base + (size_t)(nt * 16 + ln) * 2048 + cc);
          #pragma unroll
          for (int nt = 0; nt < 4; ++nt)
            acc[nt] = __builtin_amdgcn_mfma_f32_16x16x32_bf16(
                wreg[kt], bf[nt], acc[nt], 0, 0, 0);
        }
      }
    }

    // ---- this wave's K-partial -> its LDS buffer; arrive lc[0] (lane 0) ----
    {
      float* bb = bufh + wv * PB;
      #pragma unroll
      for (int nt = 0; nt < 4; ++nt)
        #pragma unroll
        for (int j = 0; j < 4; ++j)
          bb[(qq * 4 + j) * RST + nt * 16 + ln] = acc[nt][j];
    }
    asm volatile("s_waitcnt lgkmcnt(0)" ::: "memory");
    if (l0) lds_add(lc + 0);
    lds_wait(lc + 0, 4u * (t + 1));

    // ---- gate math: this thread owns dim gk x batch b (1 cell) ----
    float gv[4];
    #pragma unroll
    for (int gt = 0; gt < 4; ++gt) {
      float s = (gt == 0) ? bsf : (gt == 1) ? bsi : (gt == 2) ? bso : bsc;
      #pragma unroll
      for (int p = 0; p < 4; ++p)
        s += bufh[p * PB + (gt * 4 + d) * RST + b];
      gv[gt] = s;
    }
    asm volatile("s_waitcnt lgkmcnt(0)" ::: "memory");
    if (l0) lds_add(lc + 2);                // this wave consumed the partials

    if (LAYER == 0 && t >= BOUND && war < 256u)
      wait_flag(AGG1(cnt, t - BOUND), 256u);   // don't lead L1 by > BOUND steps

    cst = sigm(gv[0]) * cst + sigm(gv[1]) * tanh_(gv[3]);
    const float h = sigm(gv[2]) * tanh_(cst);
    const float hn = __shfl_down(h, 1);     // neighbor dim d+1 (same wave)
    if ((d & 1) == 0) {
      const unsigned pk = (unsigned)f2bf(h) | ((unsigned)f2bf(hn) << 16);
      const size_t oe = (size_t)so1 * SLOT_E + (size_t)b * 2048
                      + (LAYER == 0 ? 1024 : 0) + gk;
      __hip_atomic_store((unsigned*)state + (oe >> 1), pk, __ATOMIC_RELAXED, AGENT);
    }
    asm volatile("s_waitcnt vmcnt(0)" ::: "memory");
    if (l0) lds_add(lc + 1);                // this wave's h-stores are drained
    if (th == 0) {
      lds_wait(lc + 1, 4u * (t + 1));       // all 4 waves' h-stores visible
      __hip_atomic_fetch_add(FLG(cnt, LAYER, t) + (w >> 5), 1u,
                             __ATOMIC_RELAXED, AGENT);
      if (LAYER == 1)
        __hip_atomic_fetch_add(AGG1(cnt, t), 1u, __ATOMIC_RELAXED, AGENT);
    }
  }
}

// 256 WGs x 512 thr (1/CU, full GPU): waves 0-3 = L0 slice gw, waves 4-7 = L1
// slice gw. Each SIMD hosts one L0 wave + one L1 wave -> decorrelated stalls.
__launch_bounds__(NTHR, 1)
__global__ void lstm_k(const unsigned short* __restrict__ xs,
                       unsigned short* __restrict__ state,
                       unsigned* __restrict__ cnt,
                       const float* __restrict__ Wf0, const float* __restrict__ Wi0,
                       const float* __restrict__ Wo0, const float* __restrict__ Wc0,
                       const float* __restrict__ bf0, const float* __restrict__ bi0,
                       const float* __restrict__ bo0, const float* __restrict__ bc0,
                       const float* __restrict__ Wf1, const float* __restrict__ Wi1,
                       const float* __restrict__ Wo1, const float* __restrict__ Wc1,
                       const float* __restrict__ bf1, const float* __restrict__ bi1,
                       const float* __restrict__ bo1, const float* __restrict__ bc1)
{
  __shared__ __align__(16) float buf[8 * PB];   // 33.8 KB: L0 waves 0-3, L1 waves 4-7
  __shared__ unsigned lc[2][8];
  const int tid = threadIdx.x;
  const int gw  = blockIdx.x;

  if (tid < 16) ((unsigned*)lc)[tid] = 0u;
  // zero ring slot 0 (h0(-1) = h1(-1) = 0): 65536 u32 over first 128 WGs
  {
    const int idx = gw * NTHR + tid;
    if (idx < 65536)
      __hip_atomic_store((unsigned*)state + idx, 0u, __ATOMIC_RELAXED, AGENT);
  }
  __syncthreads();   // the only whole-WG barrier (pre-loop)
  if (tid == 0)
    __hip_atomic_fetch_add(INITC(cnt), 1u, __ATOMIC_RELAXED, AGENT);

  if (tid < 256)
    run_half<0>(xs, state, cnt, Wf0, Wi0, Wo0, Wc0, bf0, bi0, bo0, bc0,
                buf, lc[0], gw, tid);
  else
    run_half<1>(nullptr, state, cnt, Wf1, Wi1, Wo1, Wc1, bf1, bi1, bo1, bc1,
                buf + 4 * PB, lc[1], gw, tid - 256);
}

// ---------------- final projection: y[b][v] = h1(511) . Wy[v] + by[v] ----------------
__global__ void final_k(const float* __restrict__ Wy,                // [VOCAB][1024] f32
                        const unsigned short* __restrict__ hlast,    // [64][2048] lo-half
                        const float* __restrict__ by,
                        float* __restrict__ out)                     // [64][VOCAB] f32
{
  const int tid = threadIdx.x, lane = tid & 63, wid = tid >> 6;
  const int ln = lane & 15, qq = lane >> 4;
  const int vbase = (blockIdx.x * 4 + wid) * 16;
  f32x4 acc[4] = {};
  const float* arow = Wy + (size_t)(vbase + ln) * HIDDEN;
  for (int kt = 0; kt < 32; ++kt) {
    const int kk = kt * 32 + qq * 8;
    f32x4 lo = *(const f32x4*)(arow + kk);
    f32x4 hi = *(const f32x4*)(arow + kk + 4);
    short8 a;
    a[0] = (short)f2bf(lo[0]); a[1] = (short)f2bf(lo[1]);
    a[2] = (short)f2bf(lo[2]); a[3] = (short)f2bf(lo[3]);
    a[4] = (short)f2bf(hi[0]); a[5] = (short)f2bf(hi[1]);
    a[6] = (short)f2bf(hi[2]); a[7] = (short)f2bf(hi[3]);
    #pragma unroll
    for (int nt = 0; nt < 4; ++nt) {
      short8 bv = *(const short8*)(hlast + (size_t)(nt * 16 + ln) * 2048 + kk);
      acc[nt] = __builtin_amdgcn_mfma_f32_16x16x32_bf16(a, bv, acc[nt], 0, 0, 0);
    }
  }
  const int v0 = vbase + qq * 4;
  const f32x4 bias = *(const f32x4*)(by + v0);
  #pragma unroll
  for (int nt = 0; nt < 4; ++nt) {
    const int bb = nt * 16 + ln;
    f32x4 r = acc[nt] + bias;
    *(f32x4*)(out + (size_t)bb * VOCAB + v0) = r;
  }
}

// ---------------- host ----------------
extern "C" void kernel_launch(void* const* d_in, const int* in_sizes, int n_in,
                              void* d_out, int out_size, void* d_ws, size_t ws_size,
                              hipStream_t stream) {
  (void)in_sizes; (void)n_in; (void)out_size; (void)ws_size;
  const int*   texts = (const int*)d_in[0];
  const float* emb   = (const float*)d_in[1];
  const float* Wf0 = (const float*)d_in[2];  const float* bf0 = (const float*)d_in[3];
  const float* Wi0 = (const float*)d_in[4];  const float* bi0 = (const float*)d_in[5];
  const float* Wo0 = (const float*)d_in[6];  const float* bo0 = (const float*)d_in[7];
  const float* Wc0 = (const float*)d_in[8];  const float* bc0 = (const float*)d_in[9];
  const float* Wf1 = (const float*)d_in[10]; const float* bf1 = (const float*)d_in[11];
  const float* Wi1 = (const float*)d_in[12]; const float* bi1 = (const float*)d_in[13];
  const float* Wo1 = (const float*)d_in[14]; const float* bo1 = (const float*)d_in[15];
  const float* Wc1 = (const float*)d_in[16]; const float* bc1 = (const float*)d_in[17];
  const float* Wy  = (const float*)d_in[18]; const float* by  = (const float*)d_in[19];

  char* ws = (char*)d_ws;
  // ws layout (bytes): [0] flags/counters (256KB) | 262144 state ring 260x64x2048 bf16
  // (68,157,440) | 68,419,584 xs 512x64x512 bf16 (33,554,432) | end 101,974,016
  unsigned*       cnt   = (unsigned*)ws;
  unsigned short* state = (unsigned short*)(ws + 262144);
  unsigned short* xs    = (unsigned short*)(ws + 262144 + (size_t)RING * SLOT_E * 2);
  float* out = (float*)d_out;

  hipMemsetAsync(cnt, 0, 262144, stream);   // reset all flags every call
  embed_k<<<T_SEQ * NBATCH, 256, 0, stream>>>(texts, emb, xs);
  lstm_k<<<NWG, NTHR, 0, stream>>>(xs, state, cnt,
                                   Wf0, Wi0, Wo0, Wc0, bf0, bi0, bo0, bc0,
                                   Wf1, Wi1, Wo1, Wc1, bf1, bi1, bo1, bc1);
  // h1(511) lives in slot 512 % RING = 252, cols 0..1023
  final_k<<<VOCAB / 64, 256, 0, stream>>>(
      Wy, state + (size_t)(T_SEQ % RING) * SLOT_E, by, out);
}

// Round 10
// 9403.769 us; speedup vs baseline: 2.0317x; 2.0317x over previous
//
#include <hip/hip_runtime.h>
#include <stdint.h>
#include <stddef.h>

#define T_SEQ  512
#define NBATCH 64
#define EMBED  512
#define HIDDEN 1024
#define VOCAB  32000
#define NWG    128                    // 64 L0 WGs + 64 L1 WGs, 512 thr each
#define NTHR   512
#define AGENT  __HIP_MEMORY_SCOPE_AGENT
#define WGSCOPE __HIP_MEMORY_SCOPE_WORKGROUP
#define RING   260                    // h ring slots: [64][ h1(1024) | h0(1024) ] bf16
#define SLOT_E (NBATCH * 2048)
#define BOUND  250                    // max L0 lead over L1

#define RST   66                      // reduce-buffer row stride (floats)
#define PB    (32 * RST)              // one wave's partial: 32 rows x 64 batch

// flag line for (layer l, step t): 8 chunk counters (128 h-dims each) in one
// 128B line. chunk c's producers: the 8 WGs with (w>>3)==c; target 8.
#define FLG(cnt, l, t)  ((cnt) + ((((t) << 1) | (l)) << 5))
#define AGG1(cnt, t)    ((cnt) + ((1024 + (t)) << 5))   // L1 per-step aggregate, target 64
#define INITC(cnt)      ((cnt) + (1540 << 5))           // init rendezvous, target 128

typedef __attribute__((ext_vector_type(8))) short short8;
typedef __attribute__((ext_vector_type(4))) float f32x4;

__device__ __forceinline__ unsigned short f2bf(float x) {
  union { float f; unsigned u; } v; v.f = x;
  unsigned r = v.u + 0x7FFFu + ((v.u >> 16) & 1u);   // round-to-nearest-even
  return (unsigned short)(r >> 16);
}
__device__ __forceinline__ float sigm(float x) { return 1.0f / (1.0f + __expf(-x)); }
__device__ __forceinline__ float tanh_(float x) {
  float e = __expf(2.0f * x);
  return 1.0f - 2.0f / (e + 1.0f);
}

__device__ __forceinline__ unsigned ld_flag(unsigned* p) {
  return __hip_atomic_load(p, __ATOMIC_RELAXED, AGENT);
}
__device__ __forceinline__ void wait_flag(unsigned* p, unsigned tgt) {
  while (__hip_atomic_load(p, __ATOMIC_RELAXED, AGENT) < tgt)
    __builtin_amdgcn_s_sleep(1);
  asm volatile("" ::: "memory");
}
__device__ __forceinline__ void lds_add(unsigned* p) {
  __hip_atomic_fetch_add(p, 1u, __ATOMIC_RELAXED, WGSCOPE);
}
__device__ __forceinline__ void lds_wait(unsigned* p, unsigned tgt) {
  while (__hip_atomic_load(p, __ATOMIC_RELAXED, WGSCOPE) < tgt)
    __builtin_amdgcn_s_sleep(1);
  asm volatile("" ::: "memory");
}

// ---------------- embedding gather + bf16 cast: xs[t][b][e] ----------------
__global__ void embed_k(const int* __restrict__ texts, const float* __restrict__ emb,
                        unsigned short* __restrict__ xs) {
  const int bid = blockIdx.x;          // t*64 + b
  const int t = bid >> 6, b = bid & 63;
  const int row = texts[b * T_SEQ + t];
  const float* src = emb + (size_t)row * EMBED;
  const int e = threadIdx.x * 2;
  float2 v = *(const float2*)(src + e);
  unsigned pk = (unsigned)f2bf(v.x) | ((unsigned)f2bf(v.y) << 16);
  *(unsigned*)(xs + (size_t)bid * EMBED + e) = pk;
}

// ---------------- one LSTM layer: 8 waves = 4 K-quarters x 2 gate-pairs ----------------
// WG w owns dims [w*16, w*16+16). Wave (kq, gh): K-slice kq, gates {2gh, 2gh+1}.
// wreg[KT][2] <= 128 VGPR -> NO SPILL (the R4-R8 designs spilled; R3 did not).
// Ring slot s: [64][2048]: cols 0-1023 = h1(s-1), cols 1024-2047 = h0(s-1).
// L0 step t: reads slot[t] hi (h0(t-1)) + xs[t]; writes slot[t+1] hi.
// L1 step t: kq 0-1 read slot[t] lo (h1(t-1)); kq 2-3 read slot[t+1] hi (h0(t));
//            writes slot[t+1] lo.
// SIMD i hosts waves i and i+4 (different kq) -> decorrelated stall windows.
template<int LAYER>
__device__ __forceinline__ void run_layer(
    const unsigned short* __restrict__ xs_all,
    unsigned short* __restrict__ state,
    unsigned* __restrict__ cnt,
    const float* __restrict__ W0, const float* __restrict__ W1,
    const float* __restrict__ W2, const float* __restrict__ W3,
    const float* __restrict__ B0, const float* __restrict__ B1,
    const float* __restrict__ B2, const float* __restrict__ B3,
    float* buf, unsigned* lc, int w, int tid)
{
  constexpr int K  = LAYER ? 2048 : 1536;
  constexpr int KT = K / 128;              // 16 / 12 K-tiles per K-quarter
  const int lane = tid & 63;
  const int wv   = tid >> 6;               // 0..7
  const int kq   = wv >> 1;                // K-quarter 0..3
  const int gh   = wv & 1;                 // gate-pair: gates {2gh, 2gh+1}
  const int ln   = lane & 15;
  const int qq   = lane >> 4;
  const int d    = tid & 15;               // gate-math dim within 16
  const int b0   = (tid >> 4) & 31;        // gate-math batches b0, b0+32
  const bool l0  = (lane == 0);

  // ---- stage weights into VGPRs: 2 m-tiles (gate 2gh+mt, dim ln) ----
  short8 wreg[KT][2];
  #pragma unroll
  for (int mt = 0; mt < 2; ++mt) {
    const int g = 2 * gh + mt;
    const float* Wp = (g == 0) ? W0 : (g == 1) ? W1 : (g == 2) ? W2 : W3;
    const float* row = Wp + (size_t)(w * 16 + ln) * K;
    #pragma unroll
    for (int kt = 0; kt < KT; ++kt) {
      int col;
      if (LAYER == 1) col = kq * 512 + kt * 32;
      else col = (kt < 4) ? (1024 + kq * 128 + kt * 32) : (kq * 256 + (kt - 4) * 32);
      col += qq * 8;
      f32x4 lo = *(const f32x4*)(row + col);
      f32x4 hi = *(const f32x4*)(row + col + 4);
      short8 v;
      v[0] = (short)f2bf(lo[0]); v[1] = (short)f2bf(lo[1]);
      v[2] = (short)f2bf(lo[2]); v[3] = (short)f2bf(lo[3]);
      v[4] = (short)f2bf(hi[0]); v[5] = (short)f2bf(hi[1]);
      v[6] = (short)f2bf(hi[2]); v[7] = (short)f2bf(hi[3]);
      wreg[kt][mt] = v;
    }
  }
  float bs[4];
  bs[0] = B0[w * 16 + d]; bs[1] = B1[w * 16 + d];
  bs[2] = B2[w * 16 + d]; bs[3] = B3[w * 16 + d];
  float cst[2] = {0.f, 0.f};

  wait_flag(INITC(cnt), NWG);              // slot 0 zeroed everywhere

  for (int t = 0; t < T_SEQ; ++t) {
    const int so  = t % RING;
    const int so1 = (t + 1) % RING;
    const unsigned short* slotT  = state + (size_t)so  * SLOT_E;
    const unsigned short* slotT1 = state + (size_t)so1 * SLOT_E;

    unsigned war = 64;                     // ring-WAR prefetch (L0 only)
    if (LAYER == 0 && t >= BOUND) war = ld_flag(AGG1(cnt, t - BOUND));

    f32x4 acc[2][4] = {};
    if constexpr (LAYER == 0) {
      unsigned* flp = FLG(cnt, 0, (t > 0) ? t - 1 : 0) + 2 * kq;
      unsigned fv0 = 8u, fv1 = 8u;
      if (t > 0) { fv0 = ld_flag(flp); fv1 = ld_flag(flp + 1); }  // prefetch

      // x-phase (static input): overlaps flag/handoff latency
      const unsigned short* xrow = xs_all + (size_t)t * (NBATCH * EMBED);
      #pragma unroll
      for (int kt = 0; kt < 4; ++kt) {
        const int bc = kq * 128 + kt * 32 + qq * 8;
        short8 bf[4];
        #pragma unroll
        for (int nt = 0; nt < 4; ++nt)
          bf[nt] = *(const short8*)(xrow + (size_t)(nt * 16 + ln) * EMBED + bc);
        #pragma unroll
        for (int mt = 0; mt < 2; ++mt)
          #pragma unroll
          for (int nt = 0; nt < 4; ++nt)
            acc[mt][nt] = __builtin_amdgcn_mfma_f32_16x16x32_bf16(
                wreg[kt][mt], bf[nt], acc[mt][nt], 0, 0, 0);
      }
      // h-phase: 2 chunks of 128 dims, each gated by its own max-of-8 flag
      const unsigned short* hbase = slotT + 1024;
      #pragma unroll
      for (int c = 0; c < 2; ++c) {
        if (t > 0 && (c ? fv1 : fv0) < 8u) wait_flag(flp + c, 8u);
        asm volatile("" ::: "memory");
        #pragma unroll
        for (int k2 = 0; k2 < 4; ++k2) {
          const int kt = 4 + c * 4 + k2;
          const int hc = kq * 256 + c * 128 + k2 * 32 + qq * 8;
          short8 bf[4];
          #pragma unroll
          for (int nt = 0; nt < 4; ++nt)
            bf[nt] = *(const short8*)(hbase + (size_t)(nt * 16 + ln) * 2048 + hc);
          #pragma unroll
          for (int mt = 0; mt < 2; ++mt)
            #pragma unroll
            for (int nt = 0; nt < 4; ++nt)
              acc[mt][nt] = __builtin_amdgcn_mfma_f32_16x16x32_bf16(
                  wreg[kt][mt], bf[nt], acc[mt][nt], 0, 0, 0);
        }
      }
    } else {
      // kq 0-1: h1(t-1) = slot[t].lo; kq 2-3: h0(t) = slot[t+1].hi
      unsigned* flp = (kq < 2) ? FLG(cnt, 1, (t > 0) ? t - 1 : 0) + 4 * kq
                               : FLG(cnt, 0, t) + 4 * (kq - 2);
      const bool need = (kq >= 2) || (t > 0);
      unsigned fv[4] = {8u, 8u, 8u, 8u};
      if (need) {
        fv[0] = ld_flag(flp);     fv[1] = ld_flag(flp + 1);
        fv[2] = ld_flag(flp + 2); fv[3] = ld_flag(flp + 3);
      }
      const unsigned short* base = (kq < 2) ? slotT : (slotT1 + 1024);
      const int coff = (kq & 1) * 512;
      #pragma unroll
      for (int c = 0; c < 4; ++c) {
        if (need && fv[c] < 8u) wait_flag(flp + c, 8u);
        asm volatile("" ::: "memory");
        #pragma unroll
        for (int k2 = 0; k2 < 4; ++k2) {
          const int kt = c * 4 + k2;
          const int cc = coff + c * 128 + k2 * 32 + qq * 8;
          short8 bf[4];
          #pragma unroll
          for (int nt = 0; nt < 4; ++nt)
            bf[nt] = *(const short8*)(base + (size_t)(nt * 16 + ln) * 2048 + cc);
          #pragma unroll
          for (int mt = 0; mt < 2; ++mt)
            #pragma unroll
            for (int nt = 0; nt < 4; ++nt)
              acc[mt][nt] = __builtin_amdgcn_mfma_f32_16x16x32_bf16(
                  wreg[kt][mt], bf[nt], acc[mt][nt], 0, 0, 0);
        }
      }
    }

    // ---- partials: wait prev consumed, write, arrive (one per wave) ----
    lds_wait(lc + 2, 8u * t);
    {
      float* bb = buf + wv * PB;
      #pragma unroll
      for (int mt = 0; mt < 2; ++mt)
        #pragma unroll
        for (int nt = 0; nt < 4; ++nt)
          #pragma unroll
          for (int j = 0; j < 4; ++j)
            bb[(mt * 16 + qq * 4 + j) * RST + nt * 16 + ln] = acc[mt][nt][j];
    }
    asm volatile("s_waitcnt lgkmcnt(0)" ::: "memory");
    if (l0) lds_add(lc + 0);
    lds_wait(lc + 0, 8u * (t + 1));

    // ---- gate math: dim d x batches (b0, b0+32); sum 4 K-quarter partials ----
    float gv[4][2];
    #pragma unroll
    for (int g = 0; g < 4; ++g) {
      const int rr = ((g & 1) * 16 + d) * RST;
      const int wb = (g >> 1);
      #pragma unroll
      for (int s = 0; s < 2; ++s) {
        const int b = b0 + 32 * s;
        float sum = bs[g];
        #pragma unroll
        for (int p = 0; p < 4; ++p)
          sum += buf[(p * 2 + wb) * PB + rr + b];
        gv[g][s] = sum;
      }
    }
    asm volatile("s_waitcnt lgkmcnt(0)" ::: "memory");
    if (l0) lds_add(lc + 2);                // this wave consumed the partials

    if (LAYER == 0 && t >= BOUND && war < 64u)
      wait_flag(AGG1(cnt, t - BOUND), 64u);  // don't lead L1 by > BOUND steps

    #pragma unroll
    for (int s = 0; s < 2; ++s) {
      cst[s] = sigm(gv[0][s]) * cst[s] + sigm(gv[1][s]) * tanh_(gv[3][s]);
      const float h = sigm(gv[2][s]) * tanh_(cst[s]);
      const float hn = __shfl_down(h, 1);    // dim d+1, same batch
      if ((d & 1) == 0) {
        const unsigned pk = (unsigned)f2bf(h) | ((unsigned)f2bf(hn) << 16);
        const size_t oe = (size_t)so1 * SLOT_E + (size_t)(b0 + 32 * s) * 2048
                        + (LAYER == 0 ? 1024 : 0) + w * 16 + d;
        __hip_atomic_store((unsigned*)state + (oe >> 1), pk,
                           __ATOMIC_RELAXED, AGENT);
      }
    }
    asm volatile("s_waitcnt vmcnt(0)" ::: "memory");
    if (l0) lds_add(lc + 1);                // this wave's h-stores drained
    if (tid == 0) {
      lds_wait(lc + 1, 8u * (t + 1));       // all 8 waves' h-stores visible
      __hip_atomic_fetch_add(FLG(cnt, LAYER, t) + (w >> 3), 1u,
                             __ATOMIC_RELAXED, AGENT);
      if (LAYER == 1)
        __hip_atomic_fetch_add(AGG1(cnt, t), 1u, __ATOMIC_RELAXED, AGENT);
    }
  }
}

// 128 WGs x 512 thr: WGs 0-63 = L0 (16 dims each), WGs 64-127 = L1.
__launch_bounds__(NTHR, 1)
__global__ void lstm_k(const unsigned short* __restrict__ xs,
                       unsigned short* __restrict__ state,
                       unsigned* __restrict__ cnt,
                       const float* __restrict__ Wf0, const float* __restrict__ Wi0,
                       const float* __restrict__ Wo0, const float* __restrict__ Wc0,
                       const float* __restrict__ bf0, const float* __restrict__ bi0,
                       const float* __restrict__ bo0, const float* __restrict__ bc0,
                       const float* __restrict__ Wf1, const float* __restrict__ Wi1,
                       const float* __restrict__ Wo1, const float* __restrict__ Wc1,
                       const float* __restrict__ bf1, const float* __restrict__ bi1,
                       const float* __restrict__ bo1, const float* __restrict__ bc1)
{
  __shared__ __align__(16) float buf[8 * PB];   // 67.6 KB
  __shared__ unsigned lc[8];
  const int tid = threadIdx.x;
  const int gw  = blockIdx.x;

  if (tid < 8) lc[tid] = 0u;
  // zero ring slot 0 (h0(-1) = h1(-1) = 0): 65536 u32 over 128 WGs x 512 thr
  __hip_atomic_store((unsigned*)state + gw * NTHR + tid, 0u,
                     __ATOMIC_RELAXED, AGENT);
  __syncthreads();   // only whole-WG barrier (pre-loop)
  if (tid == 0)
    __hip_atomic_fetch_add(INITC(cnt), 1u, __ATOMIC_RELAXED, AGENT);

  if (gw < 64)
    run_layer<0>(xs, state, cnt, Wf0, Wi0, Wo0, Wc0, bf0, bi0, bo0, bc0,
                 buf, lc, gw, tid);
  else
    run_layer<1>(nullptr, state, cnt, Wf1, Wi1, Wo1, Wc1, bf1, bi1, bo1, bc1,
                 buf, lc, gw - 64, tid);
}

// ---------------- final projection: y[b][v] = h1(511) . Wy[v] + by[v] ----------------
__global__ void final_k(const float* __restrict__ Wy,                // [VOCAB][1024] f32
                        const unsigned short* __restrict__ hlast,    // [64][2048] lo-half
                        const float* __restrict__ by,
                        float* __restrict__ out)                     // [64][VOCAB] f32
{
  const int tid = threadIdx.x, lane = tid & 63, wid = tid >> 6;
  const int ln = lane & 15, qq = lane >> 4;
  const int vbase = (blockIdx.x * 4 + wid) * 16;
  f32x4 acc[4] = {};
  const float* arow = Wy + (size_t)(vbase + ln) * HIDDEN;
  for (int kt = 0; kt < 32; ++kt) {
    const int kk = kt * 32 + qq * 8;
    f32x4 lo = *(const f32x4*)(arow + kk);
    f32x4 hi = *(const f32x4*)(arow + kk + 4);
    short8 a;
    a[0] = (short)f2bf(lo[0]); a[1] = (short)f2bf(lo[1]);
    a[2] = (short)f2bf(lo[2]); a[3] = (short)f2bf(lo[3]);
    a[4] = (short)f2bf(hi[0]); a[5] = (short)f2bf(hi[1]);
    a[6] = (short)f2bf(hi[2]); a[7] = (short)f2bf(hi[3]);
    #pragma unroll
    for (int nt = 0; nt < 4; ++nt) {
      short8 bv = *(const short8*)(hlast + (size_t)(nt * 16 + ln) * 2048 + kk);
      acc[nt] = __builtin_amdgcn_mfma_f32_16x16x32_bf16(a, bv, acc[nt], 0, 0, 0);
    }
  }
  const int v0 = vbase + qq * 4;
  const f32x4 bias = *(const f32x4*)(by + v0);
  #pragma unroll
  for (int nt = 0; nt < 4; ++nt) {
    const int bb = nt * 16 + ln;
    f32x4 r = acc[nt] + bias;
    *(f32x4*)(out + (size_t)bb * VOCAB + v0) = r;
  }
}

// ---------------- host ----------------
extern "C" void kernel_launch(void* const* d_in, const int* in_sizes, int n_in,
                              void* d_out, int out_size, void* d_ws, size_t ws_size,
                              hipStream_t stream) {
  (void)in_sizes; (void)n_in; (void)out_size; (void)ws_size;
  const int*   texts = (const int*)d_in[0];
  const float* emb   = (const float*)d_in[1];
  const float* Wf0 = (const float*)d_in[2];  const float* bf0 = (const float*)d_in[3];
  const float* Wi0 = (const float*)d_in[4];  const float* bi0 = (const float*)d_in[5];
  const float* Wo0 = (const float*)d_in[6];  const float* bo0 = (const float*)d_in[7];
  const float* Wc0 = (const float*)d_in[8];  const float* bc0 = (const float*)d_in[9];
  const float* Wf1 = (const float*)d_in[10]; const float* bf1 = (const float*)d_in[11];
  const float* Wi1 = (const float*)d_in[12]; const float* bi1 = (const float*)d_in[13];
  const float* Wo1 = (const float*)d_in[14]; const float* bo1 = (const float*)d_in[15];
  const float* Wc1 = (const float*)d_in[16]; const float* bc1 = (const float*)d_in[17];
  const float* Wy  = (const float*)d_in[18]; const float* by  = (const float*)d_in[19];

  char* ws = (char*)d_ws;
  // ws layout (bytes): [0] flags/counters (256KB) | 262144 state ring 260x64x2048 bf16
  // (68,157,440) | 68,419,584 xs 512x64x512 bf16 (33,554,432) | end 101,974,016
  unsigned*       cnt   = (unsigned*)ws;
  unsigned short* state = (unsigned short*)(ws + 262144);
  unsigned short* xs    = (unsigned short*)(ws + 262144 + (size_t)RING * SLOT_E * 2);
  float* out = (float*)d_out;

  hipMemsetAsync(cnt, 0, 262144, stream);   // reset all flags every call
  embed_k<<<T_SEQ * NBATCH, 256, 0, stream>>>(texts, emb, xs);
  lstm_k<<<NWG, NTHR, 0, stream>>>(xs, state, cnt,
                                   Wf0, Wi0, Wo0, Wc0, bf0, bi0, bo0, bc0,
                                   Wf1, Wi1, Wo1, Wc1, bf1, bi1, bo1, bc1);
  // h1(511) lives in slot 512 % RING = 252, cols 0..1023
  final_k<<<VOCAB / 64, 256, 0, stream>>>(
      Wy, state + (size_t)(T_SEQ % RING) * SLOT_E, by, out);
}